// Round 1
// baseline (1045.095 us; speedup 1.0000x reference)
//
#include <hip/hip_runtime.h>
#include <math.h>

#define HID 128
#define HEADS 8
#define CH 32

// ---------------- GEMM: C = act(scale*(A@B) + bias), row-major, N%64==0, K%16==0 ----------------
__global__ __launch_bounds__(256) void gemm_bias_act(
    const float* __restrict__ A, const float* __restrict__ B,
    const float* __restrict__ bias, float* __restrict__ C,
    int M, int N, int K, float scale, int do_relu)
{
  __shared__ float As[16][68];  // [k][m], padded
  __shared__ float Bs[16][68];  // [k][n], padded
  const int tid = threadIdx.x;
  const int bm = blockIdx.y * 64;
  const int bn = blockIdx.x * 64;
  const int tx = tid & 15, ty = tid >> 4;
  const int a_row = tid >> 2, a_col = (tid & 3) << 2;
  const int b_row = tid >> 4, b_col = (tid & 15) << 2;
  float acc[4][4];
#pragma unroll
  for (int i = 0; i < 4; i++)
#pragma unroll
    for (int j = 0; j < 4; j++) acc[i][j] = 0.f;

  const int gr = bm + a_row;
  for (int k0 = 0; k0 < K; k0 += 16) {
    float4 av = make_float4(0.f, 0.f, 0.f, 0.f);
    if (gr < M) av = *(const float4*)(A + (size_t)gr * K + (k0 + a_col));
    As[a_col + 0][a_row] = av.x;
    As[a_col + 1][a_row] = av.y;
    As[a_col + 2][a_row] = av.z;
    As[a_col + 3][a_row] = av.w;
    float4 bv = *(const float4*)(B + (size_t)(k0 + b_row) * N + (bn + b_col));
    *(float4*)&Bs[b_row][b_col] = bv;
    __syncthreads();
#pragma unroll
    for (int kk = 0; kk < 16; kk++) {
      float4 a4 = *(const float4*)&As[kk][ty << 2];
      float4 b4 = *(const float4*)&Bs[kk][tx << 2];
      float ar[4] = {a4.x, a4.y, a4.z, a4.w};
      float br[4] = {b4.x, b4.y, b4.z, b4.w};
#pragma unroll
      for (int i = 0; i < 4; i++)
#pragma unroll
        for (int j = 0; j < 4; j++) acc[i][j] = fmaf(ar[i], br[j], acc[i][j]);
    }
    __syncthreads();
  }
  float4 bv = *(const float4*)(bias + bn + (tx << 2));
  float bb[4] = {bv.x, bv.y, bv.z, bv.w};
#pragma unroll
  for (int i = 0; i < 4; i++) {
    int r = bm + (ty << 2) + i;
    if (r < M) {
      float o[4];
#pragma unroll
      for (int j = 0; j < 4; j++) {
        float v = acc[i][j] * scale + bb[j];
        if (do_relu) v = v > 0.f ? v : 0.f;
        o[j] = v;
      }
      *(float4*)(C + (size_t)r * N + bn + (tx << 2)) = *(float4*)o;
    }
  }
}

// ---------------- v[k,h] = sum_c W[k, h*128+c] * a[h,c]  (folds attention vec through W) --------
__global__ __launch_bounds__(256) void make_v(
    const float* __restrict__ W, const float* __restrict__ a, float* __restrict__ v)
{
  int gid = blockIdx.x * 256 + threadIdx.x;  // 0..1023
  int k = gid >> 3, h = gid & 7;
  const float* wr = W + (size_t)k * (HEADS * HID) + h * HID;
  const float* ar = a + (size_t)h * HID;
  float s = 0.f;
  for (int c = 0; c < HID; c++) s = fmaf(wr[c], ar[c], s);
  v[gid] = s;
}

// ---------------- al[n,h] = sum_k h[n,k] * v[k,h] ----------------
__global__ __launch_bounds__(256) void compute_al(
    const float* __restrict__ h, const float* __restrict__ v, float* __restrict__ al, int n)
{
  __shared__ float vs[HID * HEADS];
  for (int i = threadIdx.x; i < HID * HEADS; i += 256) vs[i] = v[i];
  __syncthreads();
  int gid = blockIdx.x * 256 + threadIdx.x;
  int row = gid >> 3, hh = gid & 7;
  if (row >= n) return;
  const float* hr = h + (size_t)row * HID;
  float s = 0.f;
  for (int k = 0; k < HID; k++) s = fmaf(hr[k], vs[k * HEADS + hh], s);
  al[gid] = s;
}

// ---------------- Wp[(h*128+k)*128 + c] = W[k*1024 + h*128 + c] ----------------
__global__ __launch_bounds__(256) void permute_w(const float* __restrict__ W, float* __restrict__ Wp)
{
  int gid = blockIdx.x * 256 + threadIdx.x;  // 0..131071
  int c = gid & (HID - 1);
  int kk = gid >> 7;          // h*128+k
  int h = kk >> 7, k = kk & (HID - 1);
  Wp[gid] = W[(size_t)k * (HEADS * HID) + h * HID + c];
}

// ---------------- CSR build ----------------
__global__ __launch_bounds__(256) void hist_k(const int* __restrict__ dst, int* __restrict__ cnt, int E)
{
  int gid = blockIdx.x * 256 + threadIdx.x;
  if (gid < E) atomicAdd(&cnt[dst[gid]], 1);
}

__global__ __launch_bounds__(1024) void scan10k(const int* __restrict__ cnt, int* __restrict__ indptr, int n)
{
  __shared__ int parts[1024];
  const int tid = threadIdx.x;
  const int base = tid * 10;
  int local[10];
  int s = 0;
#pragma unroll
  for (int j = 0; j < 10; j++) {
    int v = (base + j < n) ? cnt[base + j] : 0;
    local[j] = v; s += v;
  }
  parts[tid] = s;
  __syncthreads();
  for (int off = 1; off < 1024; off <<= 1) {
    int v = (tid >= off) ? parts[tid - off] : 0;
    __syncthreads();
    parts[tid] += v;
    __syncthreads();
  }
  int ex = parts[tid] - s;
#pragma unroll
  for (int j = 0; j < 10; j++) {
    if (base + j < n) indptr[base + j] = ex;
    ex += local[j];
  }
  if (tid == 1023) indptr[n] = parts[1023];
}

__global__ __launch_bounds__(256) void scatter_k(
    const int* __restrict__ src, const int* __restrict__ dst,
    const int* __restrict__ indptr, int* __restrict__ cursor, int* __restrict__ srcs, int E)
{
  int gid = blockIdx.x * 256 + threadIdx.x;
  if (gid < E) {
    int d = dst[gid];
    int pos = indptr[d] + atomicAdd(&cursor[d], 1);
    srcs[pos] = src[gid];
  }
}

// ---------------- per-dst segment softmax + weighted aggregation of raw h_src rows -------------
__global__ __launch_bounds__(128) void gat_edge(
    const int* __restrict__ indptr, const int* __restrict__ srcs,
    const float* __restrict__ al_s, const float* __restrict__ al_d,
    const float* __restrict__ h_src, float* __restrict__ z, int ndst)
{
  const int n = blockIdx.x;
  const int tid = threadIdx.x;
  __shared__ unsigned mu[HEADS];
  __shared__ float mf[HEADS], den[HEADS], aldn[HEADS];
  __shared__ float alpha[CH][HEADS];
  __shared__ int es[CH];
  const int base = indptr[n];
  const int deg = indptr[n + 1] - base;
  if (tid < HEADS) {
    mu[tid] = 0u;
    den[tid] = 0.f;
    aldn[tid] = al_d[(size_t)n * HEADS + tid];
  }
  __syncthreads();
  const int tot = deg * HEADS;
  // pass 1: per-head max (order-preserving uint encoding for float atomicMax)
  for (int i = tid; i < tot; i += 128) {
    int e = i >> 3, h = i & 7;
    int s = srcs[base + e];
    float v = al_s[(size_t)s * HEADS + h] + aldn[h];
    v = v > 0.f ? v : 0.2f * v;
    unsigned u = __float_as_uint(v);
    u = (u & 0x80000000u) ? ~u : (u | 0x80000000u);
    atomicMax(&mu[h], u);
  }
  __syncthreads();
  if (tid < HEADS) {
    unsigned u = mu[tid];
    mf[tid] = __uint_as_float((u & 0x80000000u) ? (u ^ 0x80000000u) : ~u);
  }
  __syncthreads();
  // pass 2: denom
  for (int i = tid; i < tot; i += 128) {
    int e = i >> 3, h = i & 7;
    int s = srcs[base + e];
    float v = al_s[(size_t)s * HEADS + h] + aldn[h];
    v = v > 0.f ? v : 0.2f * v;
    atomicAdd(&den[h], expf(v - mf[h]));
  }
  __syncthreads();
  // pass 3: chunked alpha + aggregation. thread = channel c.
  float acc[HEADS];
#pragma unroll
  for (int h = 0; h < HEADS; h++) acc[h] = 0.f;
  for (int e0 = 0; e0 < deg; e0 += CH) {
    int ne = deg - e0; if (ne > CH) ne = CH;
    if (tid < ne) es[tid] = srcs[base + e0 + tid];
    for (int i = tid; i < ne * HEADS; i += 128) {
      int e = i >> 3, h = i & 7;
      int s = srcs[base + e0 + e];
      float v = al_s[(size_t)s * HEADS + h] + aldn[h];
      v = v > 0.f ? v : 0.2f * v;
      alpha[e][h] = expf(v - mf[h]) / (den[h] + 1e-16f);
    }
    __syncthreads();
    for (int e = 0; e < ne; e++) {
      float hv = h_src[(size_t)es[e] * HID + tid];
#pragma unroll
      for (int h = 0; h < HEADS; h++) acc[h] = fmaf(alpha[e][h], hv, acc[h]);
    }
    __syncthreads();
  }
  float* zp = z + (size_t)n * (HEADS * HID) + tid;
#pragma unroll
  for (int h = 0; h < HEADS; h++) zp[h * HID] = acc[h];
}

// ---------------- mean-pool per graph (batch sorted -> binary search range) + FC ----------------
__global__ __launch_bounds__(256) void pool_fc(
    const float* __restrict__ ha2, const float* __restrict__ hb2,
    const int* __restrict__ batch_a, const int* __restrict__ batch_b,
    const float* __restrict__ fc_w, const float* __restrict__ fc_b,
    float* __restrict__ out, int na, int nb)
{
  const int g = blockIdx.x;
  const int t = threadIdx.x;
  const float* h = (t < HID) ? ha2 : hb2;
  const int* batch = (t < HID) ? batch_a : batch_b;
  const int nn = (t < HID) ? na : nb;
  const int c = t & (HID - 1);
  int lo, hi;
  { int l = 0, r = nn; while (l < r) { int m = (l + r) >> 1; if (batch[m] < g) l = m + 1; else r = m; } lo = l; }
  { int l = lo, r = nn; while (l < r) { int m = (l + r) >> 1; if (batch[m] < g + 1) l = m + 1; else r = m; } hi = l; }
  float s = 0.f;
  for (int i = lo; i < hi; i++) s += h[(size_t)i * HID + c];
  int cnt = hi - lo; if (cnt < 1) cnt = 1;
  float partial = (s / (float)cnt) * fc_w[t];
  __shared__ float red[256];
  red[t] = partial;
  __syncthreads();
  for (int off = 128; off > 0; off >>= 1) {
    if (t < off) red[t] += red[t + off];
    __syncthreads();
  }
  if (t == 0) out[g] = red[0] + fc_b[0];
}

extern "C" void kernel_launch(void* const* d_in, const int* in_sizes, int n_in,
                              void* d_out, int out_size, void* d_ws, size_t ws_size,
                              hipStream_t stream)
{
  const float* x_a = (const float*)d_in[0];
  const float* x_b = (const float*)d_in[1];
  const int* edge_ab = (const int*)d_in[2];
  const int* edge_ba = (const int*)d_in[3];
  const int* batch_a = (const int*)d_in[4];
  const int* batch_b = (const int*)d_in[5];
  const float* lin_a_w = (const float*)d_in[6];
  const float* lin_a_b = (const float*)d_in[7];
  const float* lin_b_w = (const float*)d_in[8];
  const float* lin_b_b = (const float*)d_in[9];
  const float* fc_w = (const float*)d_in[10];
  const float* fc_b = (const float*)d_in[11];

  const int NA = in_sizes[4];
  const int NB = in_sizes[5];
  const int E  = in_sizes[2] / 2;
  const int FA = in_sizes[0] / NA;
  const int FB = in_sizes[1] / NB;
  const int NG = out_size;
  const int NMAX = NA > NB ? NA : NB;

  char* w = (char*)d_ws;
  auto carve = [&](size_t bytes) -> void* {
    void* p = (void*)w;
    w += (bytes + 255) & ~(size_t)255;
    return p;
  };
  float* ha0 = (float*)carve((size_t)NA * HID * 4);
  float* hb0 = (float*)carve((size_t)NB * HID * 4);
  float* ha1 = (float*)carve((size_t)NA * HID * 4);
  float* hb1 = (float*)carve((size_t)NB * HID * 4);
  float* ha2 = (float*)carve((size_t)NA * HID * 4);
  float* hb2 = (float*)carve((size_t)NB * HID * 4);
  float* z    = (float*)carve((size_t)NMAX * HEADS * HID * 4);
  float* al_s = (float*)carve((size_t)NMAX * HEADS * 4);
  float* al_d = (float*)carve((size_t)NMAX * HEADS * 4);
  float* v_s  = (float*)carve((size_t)HID * HEADS * 4);
  float* v_d  = (float*)carve((size_t)HID * HEADS * 4);
  float* Wp   = (float*)carve((size_t)HEADS * HID * HID * 4);
  int* cnt    = (int*)carve((size_t)NMAX * 4);
  int* cursor = (int*)carve((size_t)NMAX * 4);
  int* indptr_ab = (int*)carve((size_t)(NB + 1) * 4);
  int* srcs_ab   = (int*)carve((size_t)E * 4);
  int* indptr_ba = (int*)carve((size_t)(NA + 1) * 4);
  int* srcs_ba   = (int*)carve((size_t)E * 4);
  if ((size_t)(w - (char*)d_ws) > ws_size) return;  // loud failure (out stays zero)

  // input linears: h = relu(x @ W + b)
  gemm_bias_act<<<dim3(HID / 64, (NA + 63) / 64), 256, 0, stream>>>(
      x_a, lin_a_w, lin_a_b, ha0, NA, HID, FA, 1.f, 1);
  gemm_bias_act<<<dim3(HID / 64, (NB + 63) / 64), 256, 0, stream>>>(
      x_b, lin_b_w, lin_b_b, hb0, NB, HID, FB, 1.f, 1);

  auto build_csr = [&](const int* edges, int* indptr, int* srcs, int ndst) {
    const int* srca = edges;
    const int* dsta = edges + E;
    hipMemsetAsync(cnt, 0, (size_t)ndst * 4, stream);
    hist_k<<<(E + 255) / 256, 256, 0, stream>>>(dsta, cnt, E);
    scan10k<<<1, 1024, 0, stream>>>(cnt, indptr, ndst);
    hipMemsetAsync(cursor, 0, (size_t)ndst * 4, stream);
    scatter_k<<<(E + 255) / 256, 256, 0, stream>>>(srca, dsta, indptr, cursor, srcs, E);
  };
  build_csr(edge_ab, indptr_ab, srcs_ab, NB);
  build_csr(edge_ba, indptr_ba, srcs_ba, NA);

  auto run_gat = [&](const float* hsrcF, int nsrc, const float* hdstF, int ndst,
                     const int* indptr, const int* srcs,
                     const float* Ws, const float* Wd, const float* as_, const float* ad_,
                     const float* bias, float* outp, int relu) {
    make_v<<<4, 256, 0, stream>>>(Ws, as_, v_s);
    make_v<<<4, 256, 0, stream>>>(Wd, ad_, v_d);
    compute_al<<<(nsrc * HEADS + 255) / 256, 256, 0, stream>>>(hsrcF, v_s, al_s, nsrc);
    compute_al<<<(ndst * HEADS + 255) / 256, 256, 0, stream>>>(hdstF, v_d, al_d, ndst);
    gat_edge<<<ndst, 128, 0, stream>>>(indptr, srcs, al_s, al_d, hsrcF, z, ndst);
    permute_w<<<(HEADS * HID * HID) / 256, 256, 0, stream>>>(Ws, Wp);
    // out = (z @ Wp) * (1/H) + bias  (head mean fused), optional relu
    gemm_bias_act<<<dim3(HID / 64, (ndst + 63) / 64), 256, 0, stream>>>(
        z, Wp, bias, outp, ndst, HID, HEADS * HID, 1.f / HEADS, relu);
  };

  // layer 1
  run_gat(ha0, NA, hb0, NB, indptr_ab, srcs_ab,
          (const float*)d_in[12], (const float*)d_in[13], (const float*)d_in[14],
          (const float*)d_in[15], (const float*)d_in[16], hb1, 1);
  run_gat(hb0, NB, ha0, NA, indptr_ba, srcs_ba,
          (const float*)d_in[17], (const float*)d_in[18], (const float*)d_in[19],
          (const float*)d_in[20], (const float*)d_in[21], ha1, 1);
  // layer 2
  run_gat(ha1, NA, hb1, NB, indptr_ab, srcs_ab,
          (const float*)d_in[22], (const float*)d_in[23], (const float*)d_in[24],
          (const float*)d_in[25], (const float*)d_in[26], hb2, 0);
  run_gat(hb1, NB, ha1, NA, indptr_ba, srcs_ba,
          (const float*)d_in[27], (const float*)d_in[28], (const float*)d_in[29],
          (const float*)d_in[30], (const float*)d_in[31], ha2, 0);

  pool_fc<<<NG, 256, 0, stream>>>(ha2, hb2, batch_a, batch_b, fc_w, fc_b,
                                  (float*)d_out, NA, NB);
}

// Round 2
// 733.234 us; speedup vs baseline: 1.4253x; 1.4253x over previous
//
#include <hip/hip_runtime.h>
#include <math.h>

#define HID 128
#define HEADS 8
#define CH 32

// ---------------- GEMM: C = act(scale*(A@B) + bias), row-major, N%64==0, K%16==0 ----------------
__global__ __launch_bounds__(256) void gemm_bias_act(
    const float* __restrict__ A, const float* __restrict__ B,
    const float* __restrict__ bias, float* __restrict__ C,
    int M, int N, int K, float scale, int do_relu)
{
  __shared__ float As[16][68];  // [k][m], padded
  __shared__ float Bs[16][68];  // [k][n], padded
  const int tid = threadIdx.x;
  const int bm = blockIdx.y * 64;
  const int bn = blockIdx.x * 64;
  const int tx = tid & 15, ty = tid >> 4;
  const int a_row = tid >> 2, a_col = (tid & 3) << 2;
  const int b_row = tid >> 4, b_col = (tid & 15) << 2;
  float acc[4][4];
#pragma unroll
  for (int i = 0; i < 4; i++)
#pragma unroll
    for (int j = 0; j < 4; j++) acc[i][j] = 0.f;

  const int gr = bm + a_row;
  for (int k0 = 0; k0 < K; k0 += 16) {
    float4 av = make_float4(0.f, 0.f, 0.f, 0.f);
    if (gr < M) av = *(const float4*)(A + (size_t)gr * K + (k0 + a_col));
    As[a_col + 0][a_row] = av.x;
    As[a_col + 1][a_row] = av.y;
    As[a_col + 2][a_row] = av.z;
    As[a_col + 3][a_row] = av.w;
    float4 bv = *(const float4*)(B + (size_t)(k0 + b_row) * N + (bn + b_col));
    *(float4*)&Bs[b_row][b_col] = bv;
    __syncthreads();
#pragma unroll
    for (int kk = 0; kk < 16; kk++) {
      float4 a4 = *(const float4*)&As[kk][ty << 2];
      float4 b4 = *(const float4*)&Bs[kk][tx << 2];
      float ar[4] = {a4.x, a4.y, a4.z, a4.w};
      float br[4] = {b4.x, b4.y, b4.z, b4.w};
#pragma unroll
      for (int i = 0; i < 4; i++)
#pragma unroll
        for (int j = 0; j < 4; j++) acc[i][j] = fmaf(ar[i], br[j], acc[i][j]);
    }
    __syncthreads();
  }
  float4 bv = *(const float4*)(bias + bn + (tx << 2));
  float bb[4] = {bv.x, bv.y, bv.z, bv.w};
#pragma unroll
  for (int i = 0; i < 4; i++) {
    int r = bm + (ty << 2) + i;
    if (r < M) {
      float o[4];
#pragma unroll
      for (int j = 0; j < 4; j++) {
        float v = acc[i][j] * scale + bb[j];
        if (do_relu) v = v > 0.f ? v : 0.f;
        o[j] = v;
      }
      *(float4*)(C + (size_t)r * N + bn + (tx << 2)) = *(float4*)o;
    }
  }
}

// ---------------- v[k,h] = sum_c W[k, h*128+c] * a[h,c]  (folds attention vec through W) --------
__global__ __launch_bounds__(256) void make_v(
    const float* __restrict__ W, const float* __restrict__ a, float* __restrict__ v)
{
  int gid = blockIdx.x * 256 + threadIdx.x;  // 0..1023
  int k = gid >> 3, h = gid & 7;
  const float* wr = W + (size_t)k * (HEADS * HID) + h * HID;
  const float* ar = a + (size_t)h * HID;
  float s = 0.f;
  for (int c = 0; c < HID; c++) s = fmaf(wr[c], ar[c], s);
  v[gid] = s;
}

// ---------------- al[n,h] = sum_k h[n,k] * v[k,h] ----------------
__global__ __launch_bounds__(256) void compute_al(
    const float* __restrict__ h, const float* __restrict__ v, float* __restrict__ al, int n)
{
  __shared__ float vs[HID * HEADS];
  for (int i = threadIdx.x; i < HID * HEADS; i += 256) vs[i] = v[i];
  __syncthreads();
  int gid = blockIdx.x * 256 + threadIdx.x;
  int row = gid >> 3, hh = gid & 7;
  if (row >= n) return;
  const float* hr = h + (size_t)row * HID;
  float s = 0.f;
  for (int k = 0; k < HID; k++) s = fmaf(hr[k], vs[k * HEADS + hh], s);
  al[gid] = s;
}

// ---------------- Wp[(h*128+k)*128 + c] = W[k*1024 + h*128 + c] ----------------
__global__ __launch_bounds__(256) void permute_w(const float* __restrict__ W, float* __restrict__ Wp)
{
  int gid = blockIdx.x * 256 + threadIdx.x;  // 0..131071
  int c = gid & (HID - 1);
  int kk = gid >> 7;          // h*128+k
  int h = kk >> 7, k = kk & (HID - 1);
  Wp[gid] = W[(size_t)k * (HEADS * HID) + h * HID + c];
}

// ---------------- CSR build ----------------
__global__ __launch_bounds__(256) void hist_k(const int* __restrict__ dst, int* __restrict__ cnt, int E)
{
  int gid = blockIdx.x * 256 + threadIdx.x;
  if (gid < E) atomicAdd(&cnt[dst[gid]], 1);
}

__global__ __launch_bounds__(1024) void scan10k(const int* __restrict__ cnt, int* __restrict__ indptr, int n)
{
  __shared__ int parts[1024];
  const int tid = threadIdx.x;
  const int base = tid * 10;
  int local[10];
  int s = 0;
#pragma unroll
  for (int j = 0; j < 10; j++) {
    int v = (base + j < n) ? cnt[base + j] : 0;
    local[j] = v; s += v;
  }
  parts[tid] = s;
  __syncthreads();
  for (int off = 1; off < 1024; off <<= 1) {
    int v = (tid >= off) ? parts[tid - off] : 0;
    __syncthreads();
    parts[tid] += v;
    __syncthreads();
  }
  int ex = parts[tid] - s;
#pragma unroll
  for (int j = 0; j < 10; j++) {
    if (base + j < n) indptr[base + j] = ex;
    ex += local[j];
  }
  if (tid == 1023) indptr[n] = parts[1023];
}

__global__ __launch_bounds__(256) void scatter_k(
    const int* __restrict__ src, const int* __restrict__ dst,
    const int* __restrict__ indptr, int* __restrict__ cursor, int* __restrict__ srcs, int E)
{
  int gid = blockIdx.x * 256 + threadIdx.x;
  if (gid < E) {
    int d = dst[gid];
    int pos = indptr[d] + atomicAdd(&cursor[d], 1);
    srcs[pos] = src[gid];
  }
}

// ---------------- per-dst segment softmax + weighted aggregation of raw h_src rows -------------
__global__ __launch_bounds__(128) void gat_edge(
    const int* __restrict__ indptr, const int* __restrict__ srcs,
    const float* __restrict__ al_s, const float* __restrict__ al_d,
    const float* __restrict__ h_src, float* __restrict__ z, int ndst)
{
  const int n = blockIdx.x;
  const int tid = threadIdx.x;
  __shared__ unsigned mu[HEADS];
  __shared__ float mf[HEADS], den[HEADS], aldn[HEADS];
  __shared__ float alpha[CH][HEADS];
  __shared__ int es[CH];
  const int base = indptr[n];
  const int deg = indptr[n + 1] - base;
  if (tid < HEADS) {
    mu[tid] = 0u;
    den[tid] = 0.f;
    aldn[tid] = al_d[(size_t)n * HEADS + tid];
  }
  __syncthreads();
  const int tot = deg * HEADS;
  // pass 1: per-head max (order-preserving uint encoding for float atomicMax)
  for (int i = tid; i < tot; i += 128) {
    int e = i >> 3, h = i & 7;
    int s = srcs[base + e];
    float v = al_s[(size_t)s * HEADS + h] + aldn[h];
    v = v > 0.f ? v : 0.2f * v;
    unsigned u = __float_as_uint(v);
    u = (u & 0x80000000u) ? ~u : (u | 0x80000000u);
    atomicMax(&mu[h], u);
  }
  __syncthreads();
  if (tid < HEADS) {
    unsigned u = mu[tid];
    mf[tid] = __uint_as_float((u & 0x80000000u) ? (u ^ 0x80000000u) : ~u);
  }
  __syncthreads();
  // pass 2: denom
  for (int i = tid; i < tot; i += 128) {
    int e = i >> 3, h = i & 7;
    int s = srcs[base + e];
    float v = al_s[(size_t)s * HEADS + h] + aldn[h];
    v = v > 0.f ? v : 0.2f * v;
    atomicAdd(&den[h], expf(v - mf[h]));
  }
  __syncthreads();
  // pass 3: chunked alpha + aggregation. thread = channel c.
  float acc[HEADS];
#pragma unroll
  for (int h = 0; h < HEADS; h++) acc[h] = 0.f;
  for (int e0 = 0; e0 < deg; e0 += CH) {
    int ne = deg - e0; if (ne > CH) ne = CH;
    if (tid < ne) es[tid] = srcs[base + e0 + tid];
    for (int i = tid; i < ne * HEADS; i += 128) {
      int e = i >> 3, h = i & 7;
      int s = srcs[base + e0 + e];
      float v = al_s[(size_t)s * HEADS + h] + aldn[h];
      v = v > 0.f ? v : 0.2f * v;
      alpha[e][h] = expf(v - mf[h]) / (den[h] + 1e-16f);
    }
    __syncthreads();
    for (int e = 0; e < ne; e++) {
      float hv = h_src[(size_t)es[e] * HID + tid];
#pragma unroll
      for (int h = 0; h < HEADS; h++) acc[h] = fmaf(alpha[e][h], hv, acc[h]);
    }
    __syncthreads();
  }
  float* zp = z + (size_t)n * (HEADS * HID) + tid;
#pragma unroll
  for (int h = 0; h < HEADS; h++) zp[h * HID] = acc[h];
}

// ---------------- pool: per-row dot with fc_w segment, accumulate per-graph sums ----------------
// gsum must be pre-zeroed. One wave per row; LDS per-graph partials; 8 global atomics/block.
__global__ __launch_bounds__(256) void pool_dot(
    const float* __restrict__ h, const int* __restrict__ batch,
    const float* __restrict__ wseg, float* __restrict__ gsum, int n)
{
  __shared__ float sg[HEADS];  // NG == 8
  if (threadIdx.x < 8) sg[threadIdx.x] = 0.f;
  __syncthreads();
  const int lane = threadIdx.x & 63;
  const int wv = threadIdx.x >> 6;
  const int gw = blockIdx.x * 4 + wv;
  const int tw = gridDim.x * 4;
  const float2 w2 = *(const float2*)(wseg + lane * 2);
  for (int r = gw; r < n; r += tw) {
    float2 hv = *(const float2*)(h + (size_t)r * HID + lane * 2);
    float s = hv.x * w2.x + hv.y * w2.y;
#pragma unroll
    for (int off = 32; off > 0; off >>= 1) s += __shfl_down(s, off, 64);
    if (lane == 0) atomicAdd(&sg[batch[r]], s);
  }
  __syncthreads();
  if (threadIdx.x < 8) atomicAdd(&gsum[threadIdx.x], sg[threadIdx.x]);
}

__global__ __launch_bounds__(64) void finalize_out(
    const float* __restrict__ gsum, const int* __restrict__ batch_a,
    const int* __restrict__ batch_b, const float* __restrict__ fc_b,
    float* __restrict__ out, int na, int nb, int ng)
{
  int g = threadIdx.x;
  if (g >= ng) return;
  int l, r, lo;
  // count of batch_a == g
  l = 0; r = na; while (l < r) { int m = (l + r) >> 1; if (batch_a[m] < g) l = m + 1; else r = m; } lo = l;
  r = na; while (l < r) { int m = (l + r) >> 1; if (batch_a[m] < g + 1) l = m + 1; else r = m; }
  int ca = l - lo; if (ca < 1) ca = 1;
  l = 0; r = nb; while (l < r) { int m = (l + r) >> 1; if (batch_b[m] < g) l = m + 1; else r = m; } lo = l;
  r = nb; while (l < r) { int m = (l + r) >> 1; if (batch_b[m] < g + 1) l = m + 1; else r = m; }
  int cb = l - lo; if (cb < 1) cb = 1;
  out[g] = gsum[g] / (float)ca + gsum[8 + g] / (float)cb + fc_b[0];
}

extern "C" void kernel_launch(void* const* d_in, const int* in_sizes, int n_in,
                              void* d_out, int out_size, void* d_ws, size_t ws_size,
                              hipStream_t stream)
{
  const float* x_a = (const float*)d_in[0];
  const float* x_b = (const float*)d_in[1];
  const int* edge_ab = (const int*)d_in[2];
  const int* edge_ba = (const int*)d_in[3];
  const int* batch_a = (const int*)d_in[4];
  const int* batch_b = (const int*)d_in[5];
  const float* lin_a_w = (const float*)d_in[6];
  const float* lin_a_b = (const float*)d_in[7];
  const float* lin_b_w = (const float*)d_in[8];
  const float* lin_b_b = (const float*)d_in[9];
  const float* fc_w = (const float*)d_in[10];
  const float* fc_b = (const float*)d_in[11];

  const int NA = in_sizes[4];
  const int NB = in_sizes[5];
  const int E  = in_sizes[2] / 2;
  const int FA = in_sizes[0] / NA;
  const int FB = in_sizes[1] / NB;
  const int NG = out_size;
  const int NMAX = NA > NB ? NA : NB;

  char* w = (char*)d_ws;
  auto carve = [&](size_t bytes) -> void* {
    void* p = (void*)w;
    w += (bytes + 255) & ~(size_t)255;
    return p;
  };
  float* ha0 = (float*)carve((size_t)NA * HID * 4);
  float* hb0 = (float*)carve((size_t)NB * HID * 4);
  float* ha1 = (float*)carve((size_t)NA * HID * 4);
  float* hb1 = (float*)carve((size_t)NB * HID * 4);
  float* ha2 = (float*)carve((size_t)NA * HID * 4);
  float* hb2 = (float*)carve((size_t)NB * HID * 4);
  float* z    = (float*)carve((size_t)NMAX * HEADS * HID * 4);
  float* al_s = (float*)carve((size_t)NMAX * HEADS * 4);
  float* al_d = (float*)carve((size_t)NMAX * HEADS * 4);
  float* v_s  = (float*)carve((size_t)HID * HEADS * 4);
  float* v_d  = (float*)carve((size_t)HID * HEADS * 4);
  float* Wp   = (float*)carve((size_t)HEADS * HID * HID * 4);
  float* gsum = (float*)carve((size_t)16 * 4);
  int* cnt    = (int*)carve((size_t)NMAX * 4);
  int* cursor = (int*)carve((size_t)NMAX * 4);
  int* indptr_ab = (int*)carve((size_t)(NB + 1) * 4);
  int* srcs_ab   = (int*)carve((size_t)E * 4);
  int* indptr_ba = (int*)carve((size_t)(NA + 1) * 4);
  int* srcs_ba   = (int*)carve((size_t)E * 4);
  if ((size_t)(w - (char*)d_ws) > ws_size) return;  // loud failure (out stays zero)

  // input linears: h = relu(x @ W + b)
  gemm_bias_act<<<dim3(HID / 64, (NA + 63) / 64), 256, 0, stream>>>(
      x_a, lin_a_w, lin_a_b, ha0, NA, HID, FA, 1.f, 1);
  gemm_bias_act<<<dim3(HID / 64, (NB + 63) / 64), 256, 0, stream>>>(
      x_b, lin_b_w, lin_b_b, hb0, NB, HID, FB, 1.f, 1);

  auto build_csr = [&](const int* edges, int* indptr, int* srcs, int ndst) {
    const int* srca = edges;
    const int* dsta = edges + E;
    hipMemsetAsync(cnt, 0, (size_t)ndst * 4, stream);
    hist_k<<<(E + 255) / 256, 256, 0, stream>>>(dsta, cnt, E);
    scan10k<<<1, 1024, 0, stream>>>(cnt, indptr, ndst);
    hipMemsetAsync(cursor, 0, (size_t)ndst * 4, stream);
    scatter_k<<<(E + 255) / 256, 256, 0, stream>>>(srca, dsta, indptr, cursor, srcs, E);
  };
  build_csr(edge_ab, indptr_ab, srcs_ab, NB);
  build_csr(edge_ba, indptr_ba, srcs_ba, NA);

  auto run_gat = [&](const float* hsrcF, int nsrc, const float* hdstF, int ndst,
                     const int* indptr, const int* srcs,
                     const float* Ws, const float* Wd, const float* as_, const float* ad_,
                     const float* bias, float* outp, int relu) {
    make_v<<<4, 256, 0, stream>>>(Ws, as_, v_s);
    make_v<<<4, 256, 0, stream>>>(Wd, ad_, v_d);
    compute_al<<<(nsrc * HEADS + 255) / 256, 256, 0, stream>>>(hsrcF, v_s, al_s, nsrc);
    compute_al<<<(ndst * HEADS + 255) / 256, 256, 0, stream>>>(hdstF, v_d, al_d, ndst);
    gat_edge<<<ndst, 128, 0, stream>>>(indptr, srcs, al_s, al_d, hsrcF, z, ndst);
    permute_w<<<(HEADS * HID * HID) / 256, 256, 0, stream>>>(Ws, Wp);
    // out = (z @ Wp) * (1/H) + bias  (head mean fused), optional relu
    gemm_bias_act<<<dim3(HID / 64, (ndst + 63) / 64), 256, 0, stream>>>(
        z, Wp, bias, outp, ndst, HID, HEADS * HID, 1.f / HEADS, relu);
  };

  // layer 1
  run_gat(ha0, NA, hb0, NB, indptr_ab, srcs_ab,
          (const float*)d_in[12], (const float*)d_in[13], (const float*)d_in[14],
          (const float*)d_in[15], (const float*)d_in[16], hb1, 1);
  run_gat(hb0, NB, ha0, NA, indptr_ba, srcs_ba,
          (const float*)d_in[17], (const float*)d_in[18], (const float*)d_in[19],
          (const float*)d_in[20], (const float*)d_in[21], ha1, 1);
  // layer 2
  run_gat(ha1, NA, hb1, NB, indptr_ab, srcs_ab,
          (const float*)d_in[22], (const float*)d_in[23], (const float*)d_in[24],
          (const float*)d_in[25], (const float*)d_in[26], hb2, 0);
  run_gat(hb1, NB, ha1, NA, indptr_ba, srcs_ba,
          (const float*)d_in[27], (const float*)d_in[28], (const float*)d_in[29],
          (const float*)d_in[30], (const float*)d_in[31], ha2, 0);

  // pooled mean + FC, restructured as dot-then-segment-sum
  hipMemsetAsync(gsum, 0, 16 * 4, stream);
  pool_dot<<<160, 256, 0, stream>>>(ha2, batch_a, fc_w, gsum, NA);
  pool_dot<<<160, 256, 0, stream>>>(hb2, batch_b, fc_w + HID, gsum + 8, NB);
  finalize_out<<<1, 64, 0, stream>>>(gsum, batch_a, batch_b, fc_b,
                                     (float*)d_out, NA, NB, NG);
}